// Round 1
// baseline (779.770 us; speedup 1.0000x reference)
//
#include <hip/hip_runtime.h>

#define HW (512*512)

// ---------------- Kernel A: 3x3 conv, 256 -> 8 channels, SAME pad ----------
// 64x8 output tile per 256-thread block; each thread computes 2 vertical
// pixels x 8 output channels. x staged in LDS per 8-channel chunk; weights
// read via wave-uniform indices (compiler -> s_load, SGPR FMA operand).
constexpr int TW = 64, TH = 8, CIC = 8;
constexpr int XS_ROW    = TW + 2;            // 66
constexpr int XS_PER_CI = (TH + 2) * XS_ROW; // 660
constexpr int XS_TOTAL  = CIC * XS_PER_CI;   // 5280 floats = 21.1 KB

__global__ __launch_bounds__(256) void conv3x3_k(
    const float* __restrict__ x, const float* __restrict__ cw,
    const float* __restrict__ cb, float* __restrict__ xc) {
  __shared__ float xs[XS_TOTAL];
  const int t  = threadIdx.x;
  const int tx = t & 63, ty = t >> 6;            // 64 x 4 threads
  const int bw = blockIdx.x & 7, bh = blockIdx.x >> 3;
  const int w0 = bw * TW, h0 = bh * TH;

  float acc0[8], acc1[8];
#pragma unroll
  for (int co = 0; co < 8; ++co) { acc0[co] = 0.f; acc1[co] = 0.f; }

  for (int ci0 = 0; ci0 < 256; ci0 += CIC) {
    __syncthreads();
#pragma unroll 1
    for (int idx = t; idx < XS_TOTAL; idx += 256) {
      int ci  = idx / XS_PER_CI;
      int rem = idx - ci * XS_PER_CI;
      int r   = rem / XS_ROW;
      int cc  = rem - r * XS_ROW;
      int gh = h0 + r - 1, gw = w0 + cc - 1;
      float v = 0.f;
      if ((unsigned)gh < 512u && (unsigned)gw < 512u)
        v = x[(size_t)(ci0 + ci) * HW + gh * 512 + gw];
      xs[idx] = v;
    }
    __syncthreads();

#pragma unroll
    for (int ci = 0; ci < CIC; ++ci) {
      // 4 rows x 3 cols of x cover both vertical pixels' 3x3 windows
      float xv[4][3];
#pragma unroll
      for (int r = 0; r < 4; ++r)
#pragma unroll
        for (int d = 0; d < 3; ++d)
          xv[r][d] = xs[ci * XS_PER_CI + (ty * 2 + r) * XS_ROW + tx + d];

#pragma unroll
      for (int co = 0; co < 8; ++co) {
        const float* wp = cw + ((co << 8) + ci0 + ci) * 9;  // wave-uniform
#pragma unroll
        for (int dy = 0; dy < 3; ++dy)
#pragma unroll
          for (int dx = 0; dx < 3; ++dx) {
            const float wv = wp[dy * 3 + dx];
            acc0[co] = fmaf(xv[dy][dx],     wv, acc0[co]);
            acc1[co] = fmaf(xv[dy + 1][dx], wv, acc1[co]);
          }
      }
    }
  }

  const int h = h0 + ty * 2, wcol = w0 + tx;
#pragma unroll
  for (int co = 0; co < 8; ++co) {
    const float b = cb[co];
    xc[co * HW + h * 512 + wcol]       = acc0[co] + b;
    xc[co * HW + (h + 1) * 512 + wcol] = acc1[co] + b;
  }
}

// ------------- Kernel B: argmax one-hot -> 8x8 mean pool -> unfold ---------
// One wave per 8x8 pixel cell (= one fm element per channel). Ballot-count
// argmax hits per channel; write U[c][k][m] (k = kernel elem, m = patch pos).
__global__ __launch_bounds__(256) void argmax_pool_unfold_k(
    const float* __restrict__ xc, float* __restrict__ U) {
  const int lane = threadIdx.x & 63;
  const int wv   = threadIdx.x >> 6;
  const int cell = blockIdx.x * 4 + wv;      // 0..4095
  const int hd = cell >> 6, wd = cell & 63;  // fm coords (64x64)
  const int h = hd * 8 + (lane >> 3), w = wd * 8 + (lane & 7);
  const int pix = h * 512 + w;

  float best = xc[pix];
  int bc = 0;
#pragma unroll
  for (int c = 1; c < 8; ++c) {
    float v = xc[c * HW + pix];
    if (v > best) { best = v; bc = c; }      // strict > keeps first occurrence
  }
  float myu = 0.f;
#pragma unroll
  for (int c = 0; c < 8; ++c) {
    unsigned long long mk = __ballot(bc == c);
    if (lane == c) myu = (float)__popcll(mk) * (1.0f / 64.0f);
  }
  if (lane < 8) {
    const int k = (hd & 7) * 8 + (wd & 7);   // kernel element (kh,kw)
    const int m = (hd >> 3) * 8 + (wd >> 3); // patch position (ph,pw)
    U[lane * 4096 + k * 64 + m] = myu;
  }
}

// -------- Kernel C: att = (A/nz)·U, fold, 1x1 conv, out = corr*x + x -------
// One wave per patch l (8x8 output block); lane = within-patch position m.
// U[c] (16 KB) staged in LDS per channel; attention row normalized in LDS.
__global__ __launch_bounds__(256) void att_fold_corr_k(
    const float* __restrict__ attn, const float* __restrict__ U,
    const float* __restrict__ cw, const float* __restrict__ cb,
    float* __restrict__ out) {
  __shared__ float Ul[4096];
  __shared__ float Ar[4][64];
  const int lane = threadIdx.x & 63;
  const int wv   = threadIdx.x >> 6;
  const int l    = blockIdx.x * 4 + wv;      // patch index 0..4095
  const int hq = l >> 6, wq = l & 63;
  const int h = hq * 8 + (lane >> 3), w = wq * 8 + (lane & 7);

  float corrv[8];
#pragma unroll 1
  for (int c = 0; c < 8; ++c) {
    for (int i = threadIdx.x; i < 4096; i += 256) Ul[i] = U[c * 4096 + i];
    float av = attn[((c << 12) + l) * 64 + lane];
    unsigned long long nzm = __ballot(av != 0.0f);
    float inv = 1.0f / ((float)__popcll(nzm) + 1e-5f);
    Ar[wv][lane] = av * inv;
    __syncthreads();
    float s = 0.f;
#pragma unroll
    for (int k = 0; k < 64; ++k)
      s = fmaf(Ar[wv][k], Ul[k * 64 + lane], s);
    corrv[c] = s;
    __syncthreads();
  }

  const int pix = h * 512 + w;
#pragma unroll
  for (int d = 0; d < 8; ++d) {
    float s = cb[d];
#pragma unroll
    for (int c = 0; c < 8; ++c)
      s = fmaf(corrv[c], cw[d * 8 + c], s);
    float v = out[d * HW + pix];
    out[d * HW + pix] = fmaf(s, v, v);       // corr*x + x
  }
}

extern "C" void kernel_launch(void* const* d_in, const int* in_sizes, int n_in,
                              void* d_out, int out_size, void* d_ws, size_t ws_size,
                              hipStream_t stream) {
  const float* x    = (const float*)d_in[0];
  const float* attn = (const float*)d_in[1];
  const float* cw   = (const float*)d_in[2];
  const float* cb   = (const float*)d_in[3];
  const float* qw   = (const float*)d_in[4];
  const float* qb   = (const float*)d_in[5];
  float* out = (float*)d_out;
  float* U   = (float*)d_ws;          // 8*64*64 floats = 128 KB
  float* xc  = out;                    // x_conv lives in out[0 : 2M] (8 MB)

  // output 1: verbatim attentions copy
  hipMemcpyAsync(out + 2097152, attn, 2097152 * sizeof(float),
                 hipMemcpyDeviceToDevice, stream);

  conv3x3_k<<<dim3(512), dim3(256), 0, stream>>>(x, cw, cb, xc);
  argmax_pool_unfold_k<<<dim3(1024), dim3(256), 0, stream>>>(xc, U);
  att_fold_corr_k<<<dim3(1024), dim3(256), 0, stream>>>(attn, U, qw, qb, out);
}

// Round 2
// 163.553 us; speedup vs baseline: 4.7677x; 4.7677x over previous
//
#include <hip/hip_runtime.h>

#define HW (512*512)

typedef __attribute__((ext_vector_type(8))) short bfrag;   // 8 x bf16
typedef __attribute__((ext_vector_type(4))) float ffrag;   // 4 x f32 acc

__device__ __forceinline__ unsigned short f2bf(float f) {
  unsigned int u = __float_as_uint(f);
  u += 0x7fffu + ((u >> 16) & 1u);        // round-to-nearest-even
  return (unsigned short)(u >> 16);
}

// ---------- Kernel W: pack conv weights into MFMA A-fragment layout --------
// Fragment (ciblk, tap): lane l holds W[co = l&15][ci = ciblk*32 + (l>>4)*8 + j]
// for j = 0..7 (co >= 8 -> 0). 72 fragments x 64 lanes x 16B = 72 KB.
__global__ __launch_bounds__(256) void pack_w_k(
    const float* __restrict__ cw, unsigned short* __restrict__ wp) {
  int gid = blockIdx.x * 256 + threadIdx.x;
  if (gid >= 72 * 64) return;
  int fid = gid >> 6, lane = gid & 63;
  int cib = fid / 9, tap = fid - cib * 9;
  int g = lane >> 4, m = lane & 15;
  unsigned short v[8];
#pragma unroll
  for (int j = 0; j < 8; ++j) {
    int ci = cib * 32 + g * 8 + j;
    float f = (m < 8) ? cw[(m * 256 + ci) * 9 + tap] : 0.0f;
    v[j] = f2bf(f);
  }
  *(uint4*)(wp + gid * 8) = *(const uint4*)v;
}

// ---------------- Kernel A: 3x3 conv via bf16 MFMA implicit GEMM -----------
// Tile 32w x 16h per block (512 blocks), 4 waves. Per ci-block of 32: stage
// 34x18 halo'd x-tile as bf16 in LDS [kgrp][pix][ci8]; 9 taps x 8 pixel-groups
// MFMAs per wave. Double-buffered LDS, 1 barrier per ci-block.
constexpr int SROW = 34, SPIX = 34 * 18;                 // 612 pixels
constexpr int GSTRIDE = SPIX * 16;                        // bytes per kgroup: 9792
constexpr int BUF_BYTES = 4 * GSTRIDE;                    // 39168

__global__ __launch_bounds__(256) void conv_mfma_k(
    const float* __restrict__ x, const unsigned short* __restrict__ wp,
    const float* __restrict__ cb, float* __restrict__ xc) {
  __shared__ __align__(16) char xs[2 * BUF_BYTES];
  const int tid  = threadIdx.x;
  const int wv   = tid >> 6, lane = tid & 63;
  const int g    = lane >> 4, p = lane & 15;
  const int bw   = blockIdx.x & 15, bh = blockIdx.x >> 4;
  const int w0   = bw * 32, h0 = bh * 16;

  ffrag acc[8];
#pragma unroll
  for (int i = 0; i < 8; ++i) acc[i] = ffrag{0.f, 0.f, 0.f, 0.f};

  // ---- staging: units u = hg*SPIX + pix; hg=0..7 (4 ci each), pix=r*34+c
  auto stage = [&](int t) {
    char* dst = xs + (t & 1) * BUF_BYTES;
    const int base_ci = t * 32;
#pragma unroll 1
    for (int u = tid; u < 8 * SPIX; u += 256) {
      int hg  = u / SPIX;
      int pix = u - hg * SPIX;
      int r   = pix / SROW;
      int c   = pix - r * SROW;
      int gh = h0 - 1 + r, gw = w0 - 1 + c;
      float v0 = 0.f, v1 = 0.f, v2 = 0.f, v3 = 0.f;
      if ((unsigned)gh < 512u && (unsigned)gw < 512u) {
        const float* xp = x + (size_t)(base_ci + hg * 4) * HW + gh * 512 + gw;
        v0 = xp[0]; v1 = xp[HW]; v2 = xp[2 * HW]; v3 = xp[3 * HW];
      }
      unsigned int lo = (unsigned)f2bf(v0) | ((unsigned)f2bf(v1) << 16);
      unsigned int hi = (unsigned)f2bf(v2) | ((unsigned)f2bf(v3) << 16);
      int kg = hg >> 1, half = hg & 1;
      uint2 pk; pk.x = lo; pk.y = hi;
      *(uint2*)(dst + kg * GSTRIDE + pix * 16 + half * 8) = pk;
    }
  };

  stage(0);
#pragma unroll 1
  for (int t = 0; t < 8; ++t) {
    // A fragments for this ci-block (wave-redundant, L2-resident)
    bfrag a[9];
    const unsigned short* wpt = wp + (size_t)(t * 9) * 512;
#pragma unroll
    for (int tap = 0; tap < 9; ++tap)
      a[tap] = *(const bfrag*)(wpt + tap * 512 + lane * 8);

    __syncthreads();                 // buf[t&1] fully staged
    if (t < 7) stage(t + 1);         // issue next tile's loads under compute

    const char* bp = xs + (t & 1) * BUF_BYTES + g * GSTRIDE
                   + (wv * 4 * SROW + p) * 16;
#pragma unroll
    for (int tap = 0; tap < 9; ++tap) {
      const int dy = tap / 3, dx = tap - dy * 3;
#pragma unroll
      for (int r2 = 0; r2 < 4; ++r2)
#pragma unroll
        for (int cg = 0; cg < 2; ++cg) {
          bfrag b = *(const bfrag*)(bp + ((r2 + dy) * SROW + cg * 16 + dx) * 16);
          acc[r2 * 2 + cg] =
            __builtin_amdgcn_mfma_f32_16x16x32_bf16(a[tap], b, acc[r2 * 2 + cg], 0, 0, 0);
        }
    }
  }

  // epilogue: D col = lane&15 (pixel), row = (lane>>4)*4 + reg (co, 0..7 valid)
  if (lane < 32) {
#pragma unroll
    for (int r2 = 0; r2 < 4; ++r2)
#pragma unroll
      for (int cg = 0; cg < 2; ++cg) {
        const int h = h0 + wv * 4 + r2, wcol = w0 + cg * 16 + p;
#pragma unroll
        for (int reg = 0; reg < 4; ++reg) {
          int co = g * 4 + reg;
          xc[co * HW + h * 512 + wcol] = acc[r2 * 2 + cg][reg] + cb[co];
        }
      }
  }
}

// ------------- Kernel B: argmax one-hot -> 8x8 mean pool -> unfold ---------
__global__ __launch_bounds__(256) void argmax_pool_unfold_k(
    const float* __restrict__ xc, float* __restrict__ U) {
  const int lane = threadIdx.x & 63;
  const int wv   = threadIdx.x >> 6;
  const int cell = blockIdx.x * 4 + wv;      // 0..4095
  const int hd = cell >> 6, wd = cell & 63;  // fm coords (64x64)
  const int h = hd * 8 + (lane >> 3), w = wd * 8 + (lane & 7);
  const int pix = h * 512 + w;

  float best = xc[pix];
  int bc = 0;
#pragma unroll
  for (int c = 1; c < 8; ++c) {
    float v = xc[c * HW + pix];
    if (v > best) { best = v; bc = c; }
  }
  float myu = 0.f;
#pragma unroll
  for (int c = 0; c < 8; ++c) {
    unsigned long long mk = __ballot(bc == c);
    if (lane == c) myu = (float)__popcll(mk) * (1.0f / 64.0f);
  }
  if (lane < 8) {
    const int k = (hd & 7) * 8 + (wd & 7);   // kernel element
    const int m = (hd >> 3) * 8 + (wd >> 3); // patch position
    U[lane * 4096 + k * 64 + m] = myu;
  }
}

// -------- Kernel C: att = (A/nz)·U, fold, 1x1 conv, out = corr*x + x -------
__global__ __launch_bounds__(256) void att_fold_corr_k(
    const float* __restrict__ attn, const float* __restrict__ U,
    const float* __restrict__ cw, const float* __restrict__ cb,
    float* __restrict__ out) {
  __shared__ float Ul[4096];
  __shared__ float Ar[4][64];
  const int lane = threadIdx.x & 63;
  const int wv   = threadIdx.x >> 6;
  const int l    = blockIdx.x * 4 + wv;
  const int hq = l >> 6, wq = l & 63;
  const int h = hq * 8 + (lane >> 3), w = wq * 8 + (lane & 7);

  float corrv[8];
#pragma unroll 1
  for (int c = 0; c < 8; ++c) {
    for (int i = threadIdx.x; i < 4096; i += 256) Ul[i] = U[c * 4096 + i];
    float av = attn[((c << 12) + l) * 64 + lane];
    unsigned long long nzm = __ballot(av != 0.0f);
    float inv = 1.0f / ((float)__popcll(nzm) + 1e-5f);
    Ar[wv][lane] = av * inv;
    __syncthreads();
    float s = 0.f;
#pragma unroll
    for (int k = 0; k < 64; ++k)
      s = fmaf(Ar[wv][k], Ul[k * 64 + lane], s);
    corrv[c] = s;
    __syncthreads();
  }

  const int pix = h * 512 + w;
#pragma unroll
  for (int d = 0; d < 8; ++d) {
    float s = cb[d];
#pragma unroll
    for (int c = 0; c < 8; ++c)
      s = fmaf(corrv[c], cw[d * 8 + c], s);
    float v = out[d * HW + pix];
    out[d * HW + pix] = fmaf(s, v, v);
  }
}

extern "C" void kernel_launch(void* const* d_in, const int* in_sizes, int n_in,
                              void* d_out, int out_size, void* d_ws, size_t ws_size,
                              hipStream_t stream) {
  const float* x    = (const float*)d_in[0];
  const float* attn = (const float*)d_in[1];
  const float* cw   = (const float*)d_in[2];
  const float* cb   = (const float*)d_in[3];
  const float* qw   = (const float*)d_in[4];
  const float* qb   = (const float*)d_in[5];
  float* out = (float*)d_out;

  unsigned short* wpack = (unsigned short*)d_ws;          // 72 KB
  float* U = (float*)((char*)d_ws + 73728);               // 128 KB
  float* xc = out;                                        // x_conv in out[0:2M]

  // output 1: verbatim attentions copy
  hipMemcpyAsync(out + 2097152, attn, 2097152 * sizeof(float),
                 hipMemcpyDeviceToDevice, stream);

  pack_w_k<<<dim3(18), dim3(256), 0, stream>>>(cw, wpack);
  conv_mfma_k<<<dim3(512), dim3(256), 0, stream>>>(x, wpack, cb, xc);
  argmax_pool_unfold_k<<<dim3(1024), dim3(256), 0, stream>>>(xc, U);
  att_fold_corr_k<<<dim3(1024), dim3(256), 0, stream>>>(attn, U, qw, qb, out);
}